// Round 4
// baseline (2057.977 us; speedup 1.0000x reference)
//
#include <hip/hip_runtime.h>

// ODELayer RK4 scan — R8 "4-wave, 1 wave/SIMD":
//   R7 analysis: LDS read pipe was the critical resource (160 ds_read_b128
//   per CU per eval ~ 1920 cyc > MFMA floor 1513 cyc). B-frags (activations)
//   are replicated into every wave, so per-CU LDS traffic scales with wave
//   count while MFMA instr count is fixed (312/eval split among waves).
//   R8: 256 threads = 4 waves (1/SIMD). Per-wave tiles double; per-CU LDS
//   reads halve (80/eval ~ 960 cyc). MFMA floor unchanged. ILP from 4-6
//   independent accumulator chains per stage; weight file 78 frags (312
//   VGPR) fits the 512-VGPR budget at 1 wave/EU.
//     S1: wave v -> h1-tiles {4v..4v+3} + lin-tiles {2v,2v+1} (30 MFMA)
//     S2: wave v -> h2-tiles {4v..4v+3} (32 MFMA)
//     S3: wave v -> k-tiles {2v,2v+1} (16 MFMA) + RK4 state
// Phase 2 (outnet_kernel) unchanged.

#define TSTEPS 256
#define BATCH  1024
#define NUQ    32
#define NXQ    128
#define NFQ    256
#define NINQ   160
#define NY     ((size_t)TSTEPS * BATCH * NXQ)

typedef __attribute__((ext_vector_type(8))) short bf16x8;
typedef __attribute__((ext_vector_type(4))) short s16x4;
typedef __attribute__((ext_vector_type(4))) float f32x4;
typedef unsigned short u16;

__device__ __forceinline__ u16 f2b(float f) {
  unsigned u = __float_as_uint(f);
  u = (u + 0x7FFFu + ((u >> 16) & 1u)) >> 16;
  return (u16)u;
}
__device__ __forceinline__ unsigned cvtpk(float a, float b) {
  unsigned r;
  asm("v_cvt_pk_bf16_f32 %0, %1, %2" : "=v"(r) : "v"(a), "v"(b));
  return r;
}
__device__ __forceinline__ f32x4 mfma16(bf16x8 a, bf16x8 b, f32x4 c) {
  return __builtin_amdgcn_mfma_f32_16x16x32_bf16(a, b, c, 0, 0, 0);
}
// 8 consecutive f32 weights -> bf16 fragment (16B-aligned source).
__device__ __forceinline__ bf16x8 ldw8f(const float* p) {
  f32x4 a = *reinterpret_cast<const f32x4*>(p);
  f32x4 b = *reinterpret_cast<const f32x4*>(p + 4);
  bf16x8 r;
  r[0] = (short)f2b(a[0]); r[1] = (short)f2b(a[1]);
  r[2] = (short)f2b(a[2]); r[3] = (short)f2b(a[3]);
  r[4] = (short)f2b(b[0]); r[5] = (short)f2b(b[1]);
  r[6] = (short)f2b(b[2]); r[7] = (short)f2b(b[3]);
  return r;
}

// LDS map: B-frag buffers, frag = [64 lanes][16B], frag kt at +1024*kt.
// Output tile T (16 feat x 16 batch, 512B) lives at frag T>>1, half T&1.
#define ZOFF  0       // z^T x-part: 4 frags (4 KiB)
#define H1OFF 4096    // h1^T: 8 frags (8 KiB)
#define H2OFF 12288   // h2^T: 8 frags (8 KiB)
#define SMEMB 20480

// ======================= Phase 1: the sequential scan =======================
__global__ __launch_bounds__(256, 1)
void scan_kernel(const float* __restrict__ uin,   // [256][1024][32]
                 const float* __restrict__ x0,    // [1024][128]
                 const float* __restrict__ dtp,
                 const float* __restrict__ Wlin,  // [128][160]
                 const float* __restrict__ W1,    // [256][160]
                 const float* __restrict__ b1,    // [256]
                 const float* __restrict__ W2,    // [256][256]
                 const float* __restrict__ b2,    // [256]
                 const float* __restrict__ W3,    // [128][256]
                 const float* __restrict__ b3,    // [128]
                 u16* __restrict__ xall,          // [256][1024][128] bf16
                 float* __restrict__ out)         // xf at out[NY..]
{
  __shared__ __align__(16) char smem[SMEMB];

  const int tid  = threadIdx.x;
  const int wg   = blockIdx.x;            // batch rows wg*16..+15
  const int lane = tid & 63;
  const int v    = tid >> 6;              // wave 0..3 (one per SIMD)
  const int ln   = lane & 15;             // batch index within row-group
  const int q    = lane >> 4;

  const float dt  = dtp[0];
  const float dth = 0.5f * dt;
  const float dt6 = dt * (1.0f / 6.0f);
  const f32x4 zero4 = {0.f, 0.f, 0.f, 0.f};

  // Producer-side write offset within a frag pair:
  // value (feat 16T+4q+r, batch ln) -> byte 512*T + wby (+2r inside the b64)
  const int wby = 256 * (q >> 1) + 16 * ln + 8 * (q & 1);

  // ---------------- register-resident A-fragments (weights) ----------------
  // A-frag for n-tile T, K-tile kt: lane holds W[16T+ln][32kt+8q+j], j=0..7.
  bf16x8 wc[5][4];   // W1,   h1-tiles {4v..4v+3}
  bf16x8 wl[5][2];   // Wlin, lin-tiles {2v, 2v+1}
  bf16x8 w2[8][4];   // W2,   h2-tiles {4v..4v+3}
  bf16x8 w3[8][2];   // W3,   k-tiles {2v, 2v+1}
#pragma unroll
  for (int kt = 0; kt < 5; kt++) {
#pragma unroll
    for (int i = 0; i < 4; i++)
      wc[kt][i] = ldw8f(W1 + (size_t)(16 * (4 * v + i) + ln) * NINQ + 32 * kt + 8 * q);
#pragma unroll
    for (int i = 0; i < 2; i++)
      wl[kt][i] = ldw8f(Wlin + (size_t)(16 * (2 * v + i) + ln) * NINQ + 32 * kt + 8 * q);
  }
#pragma unroll
  for (int kt = 0; kt < 8; kt++) {
#pragma unroll
    for (int i = 0; i < 4; i++)
      w2[kt][i] = ldw8f(W2 + (size_t)(16 * (4 * v + i) + ln) * NFQ + 32 * kt + 8 * q);
#pragma unroll
    for (int i = 0; i < 2; i++)
      w3[kt][i] = ldw8f(W3 + (size_t)(16 * (2 * v + i) + ln) * NFQ + 32 * kt + 8 * q);
  }

  // ---- biases in registers (barriers block LICM of in-loop reloads) ----
  f32x4 bb1[4], bb2[4], bb3[2];
#pragma unroll
  for (int i = 0; i < 4; i++) {
    bb1[i] = *reinterpret_cast<const f32x4*>(b1 + 16 * (4 * v + i) + 4 * q);
    bb2[i] = *reinterpret_cast<const f32x4*>(b2 + 16 * (4 * v + i) + 4 * q);
  }
#pragma unroll
  for (int i = 0; i < 2; i++)
    bb3[i] = *reinterpret_cast<const f32x4*>(b3 + 16 * (2 * v + i) + 4 * q);

  // RK4 state: xs[i][r] = x[batch ln][xdim 16*(2v+i)+4q+r]
  f32x4 xs[2], ksum[2], accl[2];
#pragma unroll
  for (int i = 0; i < 2; i++) {
    xs[i] = *reinterpret_cast<const f32x4*>(
        x0 + (size_t)(wg * 16 + ln) * NXQ + 16 * (2 * v + i) + 4 * q);
    uint2 p;
    p.x = cvtpk(xs[i][0], xs[i][1]);
    p.y = cvtpk(xs[i][2], xs[i][3]);
    *reinterpret_cast<uint2*>(smem + ZOFF + 512 * (2 * v + i) + wby) = p;
  }
  // u B-frag (register-resident): lane holds u[ln][8q+j]
  bf16x8 uf = ldw8f(uin + (size_t)(wg * 16 + ln) * NUQ + 8 * q);
  f32x4 ur0 = zero4, ur1 = zero4;        // raw u[t+1], issued at e==0
  __syncthreads();

#pragma unroll 1
  for (int t = 0; t < TSTEPS; t++) {
#pragma unroll 1
    for (int e = 0; e < 4; e++) {
      // ---- S1: h1^T = W1 z^T (4 tiles) + lin-tiles {2v,2v+1} (regs) ----
      {
        bf16x8 zf[4];
#pragma unroll
        for (int kt = 0; kt < 4; kt++)
          zf[kt] = *reinterpret_cast<const bf16x8*>(smem + ZOFF + 1024 * kt + 16 * lane);
        f32x4 ah[4] = {zero4, zero4, zero4, zero4};
        f32x4 al[2] = {zero4, zero4};
#pragma unroll
        for (int kt = 0; kt < 4; kt++) {
#pragma unroll
          for (int i = 0; i < 4; i++)
            ah[i] = mfma16(wc[kt][i], zf[kt], ah[i]);
#pragma unroll
          for (int i = 0; i < 2; i++)
            al[i] = mfma16(wl[kt][i], zf[kt], al[i]);
        }
#pragma unroll
        for (int i = 0; i < 4; i++)
          ah[i] = mfma16(wc[4][i], uf, ah[i]);
#pragma unroll
        for (int i = 0; i < 2; i++) {
          al[i] = mfma16(wl[4][i], uf, al[i]);
          accl[i] = al[i];
        }
#pragma unroll
        for (int i = 0; i < 4; i++) {
          uint2 p;
          p.x = cvtpk(fmaxf(ah[i][0] + bb1[i][0], 0.f), fmaxf(ah[i][1] + bb1[i][1], 0.f));
          p.y = cvtpk(fmaxf(ah[i][2] + bb1[i][2], 0.f), fmaxf(ah[i][3] + bb1[i][3], 0.f));
          *reinterpret_cast<uint2*>(smem + H1OFF + 512 * (4 * v + i) + wby) = p;
        }
      }
      __syncthreads();
      // ---- S2: h2^T = W2 h1^T (4 tiles) ----
      {
        bf16x8 g[8];
#pragma unroll
        for (int kt = 0; kt < 8; kt++)
          g[kt] = *reinterpret_cast<const bf16x8*>(smem + H1OFF + 1024 * kt + 16 * lane);
        f32x4 d[4] = {zero4, zero4, zero4, zero4};
#pragma unroll
        for (int kt = 0; kt < 8; kt++) {
#pragma unroll
          for (int i = 0; i < 4; i++)
            d[i] = mfma16(w2[kt][i], g[kt], d[i]);
        }
#pragma unroll
        for (int i = 0; i < 4; i++) {
          uint2 p;
          p.x = cvtpk(fmaxf(d[i][0] + bb2[i][0], 0.f), fmaxf(d[i][1] + bb2[i][1], 0.f));
          p.y = cvtpk(fmaxf(d[i][2] + bb2[i][2], 0.f), fmaxf(d[i][3] + bb2[i][3], 0.f));
          *reinterpret_cast<uint2*>(smem + H2OFF + 512 * (4 * v + i) + wby) = p;
        }
      }
      __syncthreads();
      // u[t+1]: issue raw loads early (e==0), convert late (e==3)
      if (e == 0 && t + 1 < TSTEPS) {
        const float* up = uin + ((size_t)(t + 1) * BATCH + wg * 16 + ln) * NUQ + 8 * q;
        ur0 = *reinterpret_cast<const f32x4*>(up);
        ur1 = *reinterpret_cast<const f32x4*>(up + 4);
      }
      if (e == 3 && t + 1 < TSTEPS) {
#pragma unroll
        for (int j = 0; j < 4; j++) {
          uf[j]     = (short)f2b(ur0[j]);
          uf[4 + j] = (short)f2b(ur1[j]);
        }
      }
      // ---- S3: k-tiles {2v,2v+1} = W3 h2^T + lin + b3 ; RK4 update ----
      {
        bf16x8 g[8];
#pragma unroll
        for (int kt = 0; kt < 8; kt++)
          g[kt] = *reinterpret_cast<const bf16x8*>(smem + H2OFF + 1024 * kt + 16 * lane);
        f32x4 ka[2] = {zero4, zero4}, kb[2] = {zero4, zero4};  // 4 chains d4
#pragma unroll
        for (int j = 0; j < 4; j++) {
#pragma unroll
          for (int i = 0; i < 2; i++) {
            ka[i] = mfma16(w3[j][i], g[j], ka[i]);
            kb[i] = mfma16(w3[4 + j][i], g[4 + j], kb[i]);
          }
        }
        const float wk = (e == 1 || e == 2) ? 2.0f : 1.0f;
        const float cn = (e == 2) ? dt : dth;
#pragma unroll
        for (int i = 0; i < 2; i++) {
          float xe[4];
#pragma unroll
          for (int r = 0; r < 4; r++) {
            float kv = ka[i][r] + kb[i][r] + accl[i][r] + bb3[i][r];
            if (e == 0) ksum[i][r] = kv; else ksum[i][r] += wk * kv;
            if (e == 3) { xs[i][r] += dt6 * ksum[i][r]; xe[r] = xs[i][r]; }
            else        { xe[r] = xs[i][r] + cn * kv; }
          }
          uint2 p;
          p.x = cvtpk(xe[0], xe[1]);
          p.y = cvtpk(xe[2], xe[3]);
          *reinterpret_cast<uint2*>(smem + ZOFF + 512 * (2 * v + i) + wby) = p;
          if (e == 3)
            *reinterpret_cast<uint2*>(
                xall + ((size_t)t * BATCH + wg * 16 + ln) * NXQ + 16 * (2 * v + i) + 4 * q) = p;
        }
      }
      __syncthreads();
    }
  }

  // x_final (f32), vectorized
#pragma unroll
  for (int i = 0; i < 2; i++)
    *reinterpret_cast<f32x4*>(
        out + NY + (size_t)(wg * 16 + ln) * NXQ + 16 * (2 * v + i) + 4 * q) = xs[i];
}

// ======================= Phase 2: bulk out_net GEMM =========================
// Processes y rows [16*slab .. ) for slabs in [slab0+blk*spw, slab_end).
__global__ __launch_bounds__(512, 2)
void outnet_kernel(const u16* __restrict__ xall,  // [rows][128] bf16
                   const float* __restrict__ Wo1, const float* __restrict__ bo1,
                   const float* __restrict__ Wo2, const float* __restrict__ bo2,
                   const float* __restrict__ Wo3, const float* __restrict__ bo3,
                   float* __restrict__ out,       // y [rows][128] f32
                   int slab0, int slab_end, int spw)
{
  __shared__ u16 h1[2][16][264];
  __shared__ u16 h2[2][16][264];

  const int tid  = threadIdx.x;
  const int lane = tid & 63;
  const int v    = tid >> 6;
  const int ln   = lane & 15;
  const int q    = lane >> 4;
  const int n1   = 16 * v + ln;
  const int n2   = 128 + n1;
  const f32x4 zero4 = {0.f, 0.f, 0.f, 0.f};

  bf16x8 f1[4][2];
#pragma unroll
  for (int kt = 0; kt < 4; kt++) {
    int k = 32 * kt + 8 * q;
    f1[kt][0] = ldw8f(Wo1 + n1 * NXQ + k);
    f1[kt][1] = ldw8f(Wo1 + n2 * NXQ + k);
  }
  bf16x8 f2[8][2];
#pragma unroll
  for (int kt = 0; kt < 8; kt++) {
    int k = 32 * kt + 8 * q;
    f2[kt][0] = ldw8f(Wo2 + n1 * NFQ + k);
    f2[kt][1] = ldw8f(Wo2 + n2 * NFQ + k);
  }
  bf16x8 f3[8];
#pragma unroll
  for (int kt = 0; kt < 8; kt++)
    f3[kt] = ldw8f(Wo3 + n1 * NFQ + 32 * kt + 8 * q);

  const float c1a = bo1[n1], c1b = bo1[n2];
  const float c2a = bo2[n1], c2b = bo2[n2];
  const float c3  = bo3[n1];

  const int s0  = slab0 + (int)blockIdx.x * spw;
  int cnt = slab_end - s0; if (cnt > spw) cnt = spw;
  if (cnt <= 0) return;

  bf16x8 a[4], an[4];
#pragma unroll
  for (int kt = 0; kt < 4; kt++)
    a[kt] = *reinterpret_cast<const bf16x8*>(
        &xall[((size_t)16 * s0 + ln) * NXQ + 32 * kt + 8 * q]);

#pragma unroll 1
  for (int i = 0; i < cnt; i++) {
    const int s = s0 + i, par = i & 1;
    if (i + 1 < cnt) {
#pragma unroll
      for (int kt = 0; kt < 4; kt++)
        an[kt] = *reinterpret_cast<const bf16x8*>(
            &xall[((size_t)16 * (s + 1) + ln) * NXQ + 32 * kt + 8 * q]);
    }
    // o1
    {
      f32x4 d0 = zero4, d1 = zero4;
#pragma unroll
      for (int kt = 0; kt < 4; kt++) {
        d0 = mfma16(a[kt], f1[kt][0], d0);
        d1 = mfma16(a[kt], f1[kt][1], d1);
      }
#pragma unroll
      for (int r = 0; r < 4; r++) {
        h1[par][4 * q + r][n1] = f2b(fmaxf(d0[r] + c1a, 0.f));
        h1[par][4 * q + r][n2] = f2b(fmaxf(d1[r] + c1b, 0.f));
      }
    }
    __syncthreads();
    // o2
    {
      bf16x8 c[8];
#pragma unroll
      for (int kt = 0; kt < 8; kt++)
        c[kt] = *reinterpret_cast<const bf16x8*>(&h1[par][ln][32 * kt + 8 * q]);
      f32x4 e0 = zero4, e1 = zero4;
#pragma unroll
      for (int kt = 0; kt < 8; kt++) {
        e0 = mfma16(c[kt], f2[kt][0], e0);
        e1 = mfma16(c[kt], f2[kt][1], e1);
      }
#pragma unroll
      for (int r = 0; r < 4; r++) {
        h2[par][4 * q + r][n1] = f2b(fmaxf(e0[r] + c2a, 0.f));
        h2[par][4 * q + r][n2] = f2b(fmaxf(e1[r] + c2b, 0.f));
      }
    }
    __syncthreads();
    // o3 -> y (f32); no trailing barrier (ping-pong buffers)
    {
      bf16x8 g[8];
#pragma unroll
      for (int kt = 0; kt < 8; kt++)
        g[kt] = *reinterpret_cast<const bf16x8*>(&h2[par][ln][32 * kt + 8 * q]);
      f32x4 y = zero4;
#pragma unroll
      for (int kt = 0; kt < 8; kt++) y = mfma16(g[kt], f3[kt], y);
#pragma unroll
      for (int r = 0; r < 4; r++)
        out[((size_t)16 * s + 4 * q + r) * NXQ + n1] = y[r] + c3;
    }
#pragma unroll
    for (int kt = 0; kt < 4; kt++) a[kt] = an[kt];
  }
}

extern "C" void kernel_launch(void* const* d_in, const int* in_sizes, int n_in,
                              void* d_out, int out_size, void* d_ws, size_t ws_size,
                              hipStream_t stream) {
  const float* uin  = (const float*)d_in[0];
  const float* x0   = (const float*)d_in[1];
  const float* dtp  = (const float*)d_in[2];
  const float* Wlin = (const float*)d_in[3];
  const float* W1   = (const float*)d_in[4];
  const float* b1   = (const float*)d_in[5];
  const float* W2   = (const float*)d_in[6];
  const float* b2   = (const float*)d_in[7];
  const float* W3   = (const float*)d_in[8];
  const float* b3   = (const float*)d_in[9];
  const float* Wo1  = (const float*)d_in[10];
  const float* bo1  = (const float*)d_in[11];
  const float* Wo2  = (const float*)d_in[12];
  const float* bo2  = (const float*)d_in[13];
  const float* Wo3  = (const float*)d_in[14];
  const float* bo3  = (const float*)d_in[15];
  float* out = (float*)d_out;

  const size_t xall_bytes = NY * sizeof(u16);   // 64 MiB
  const bool ws_ok = (ws_size >= xall_bytes);
  u16* xall = ws_ok ? (u16*)d_ws : (u16*)d_out;  // fallback: front of y region

  scan_kernel<<<dim3(64), dim3(256), 0, stream>>>(
      uin, x0, dtp, Wlin, W1, b1, W2, b2, W3, b3, xall, out);

  const int nslab = TSTEPS * BATCH / 16;        // 16384
  if (ws_ok) {
    const int spw = 32;
    outnet_kernel<<<dim3(nslab / spw), dim3(512), 0, stream>>>(
        xall, Wo1, bo1, Wo2, bo2, Wo3, bo3, out, 0, nslab, spw);
  } else {
    // y[slab s] overwrites x-slabs [2s,2s+2): process [S,2S) in halving
    // passes so clobbered x-slabs are always already consumed.
    for (int S = nslab / 2; S >= 1; S >>= 1) {
      int grid = S < 512 ? S : 512;
      int spw  = (S + grid - 1) / grid;
      outnet_kernel<<<dim3(grid), dim3(512), 0, stream>>>(
          xall, Wo1, bo1, Wo2, bo2, Wo3, bo3, out, S, 2 * S, spw);
    }
    outnet_kernel<<<dim3(1), dim3(512), 0, stream>>>(
        xall, Wo1, bo1, Wo2, bo2, Wo3, bo3, out, 0, 1, 1);
  }
}

// Round 5
// 1380.004 us; speedup vs baseline: 1.4913x; 1.4913x over previous
//
#include <hip/hip_runtime.h>

// ODELayer RK4 scan — R9 "fp8 activations for S2/S3 + lgkmcnt-only barriers".
//   Structure = R7 (8 waves, balanced swapped-operand; best = 1243 µs scan).
//   R8 lesson: weight file must stay <= ~40 frags/wave (256 arch-VGPR cap);
//   keep 8 waves and cut LDS BYTES instead of wave count:
//   * h1/h2 stored as fp8 e4m3 (512B/K-frag); two K-frags per ds_read_b128
//     -> per-CU reads 160 -> 96 per eval. S2/S3 MFMA = fp8_fp8 (bf16 rate,
//     count unchanged) -> kernel becomes MFMA-bound (~1513 cyc floor).
//   * exact power-of-2 scales vs e4m3 subnormal floor (weights std 1e-4):
//     h1 x2^9, W2/W3 x2^11, h2 x2^16; descale 2^-4 / 2^-27 in f32 epilogue.
//     Accuracy-critical lin path + S1 stay bf16.
//   * in-loop barriers = s_waitcnt lgkmcnt(0) + s_barrier (no vmcnt drain:
//     xall stores / u prefetch have no cross-wave consumers).
// Phase 2 (outnet_kernel) unchanged.

#define TSTEPS 256
#define BATCH  1024
#define NUQ    32
#define NXQ    128
#define NFQ    256
#define NINQ   160
#define NY     ((size_t)TSTEPS * BATCH * NXQ)

typedef __attribute__((ext_vector_type(8))) short bf16x8;
typedef __attribute__((ext_vector_type(4))) short s16x4;
typedef __attribute__((ext_vector_type(4))) float f32x4;
typedef unsigned short u16;

__device__ __forceinline__ u16 f2b(float f) {
  unsigned u = __float_as_uint(f);
  u = (u + 0x7FFFu + ((u >> 16) & 1u)) >> 16;
  return (u16)u;
}
__device__ __forceinline__ unsigned cvtpk(float a, float b) {
  unsigned r;
  asm("v_cvt_pk_bf16_f32 %0, %1, %2" : "=v"(r) : "v"(a), "v"(b));
  return r;
}
__device__ __forceinline__ f32x4 mfma16(bf16x8 a, bf16x8 b, f32x4 c) {
  return __builtin_amdgcn_mfma_f32_16x16x32_bf16(a, b, c, 0, 0, 0);
}
__device__ __forceinline__ f32x4 mfma8(long a, long b, f32x4 c) {
  return __builtin_amdgcn_mfma_f32_16x16x32_fp8_fp8(a, b, c, 0, 0, 0);
}
// 8 consecutive f32 weights -> bf16 fragment (16B-aligned source).
__device__ __forceinline__ bf16x8 ldw8f(const float* p) {
  f32x4 a = *reinterpret_cast<const f32x4*>(p);
  f32x4 b = *reinterpret_cast<const f32x4*>(p + 4);
  bf16x8 r;
  r[0] = (short)f2b(a[0]); r[1] = (short)f2b(a[1]);
  r[2] = (short)f2b(a[2]); r[3] = (short)f2b(a[3]);
  r[4] = (short)f2b(b[0]); r[5] = (short)f2b(b[1]);
  r[6] = (short)f2b(b[2]); r[7] = (short)f2b(b[3]);
  return r;
}
// 8 consecutive f32 weights -> scaled fp8 e4m3 fragment (i64 = 8 bytes).
__device__ __forceinline__ long ldw8f8(const float* p, float s) {
  f32x4 a = *reinterpret_cast<const f32x4*>(p);
  f32x4 b = *reinterpret_cast<const f32x4*>(p + 4);
  int lo = 0, hi = 0;
  lo = __builtin_amdgcn_cvt_pk_fp8_f32(a[0] * s, a[1] * s, lo, false);
  lo = __builtin_amdgcn_cvt_pk_fp8_f32(a[2] * s, a[3] * s, lo, true);
  hi = __builtin_amdgcn_cvt_pk_fp8_f32(b[0] * s, b[1] * s, hi, false);
  hi = __builtin_amdgcn_cvt_pk_fp8_f32(b[2] * s, b[3] * s, hi, true);
  return (long)(unsigned)lo | ((long)hi << 32);
}
// LDS-only barrier: no vmcnt drain (no cross-wave global-memory consumers).
__device__ __forceinline__ void bar_lds() {
  asm volatile("s_waitcnt lgkmcnt(0)" ::: "memory");
  __builtin_amdgcn_s_barrier();
  asm volatile("" ::: "memory");
}

// LDS map:
//  z  (bf16): 4 frags x 1KB. frag = [64 lanes][16B]; tile T at frag T>>1,
//             half T&1 (producer byte: 512*(T&1)+256*(q>>1)+16*ln+8*(q&1)+2r).
//  h1,h2 (fp8): 4 pair-frags x 1KB; lane L byte pair [16L,16L+8)=kt even,
//             [16L+8,16L+16)=kt odd. Producer byte for tile T (this lane):
//             1024*(T>>2)+256*(2*(T&1)+(q>>1))+16*ln+8*((T>>1)&1)+4*(q&1).
#define ZOFF  0
#define H1OFF 4096
#define H2OFF 8192
#define SMEMB 12288

// ======================= Phase 1: the sequential scan =======================
__global__ __launch_bounds__(512, 2)
void scan_kernel(const float* __restrict__ uin,   // [256][1024][32]
                 const float* __restrict__ x0,    // [1024][128]
                 const float* __restrict__ dtp,
                 const float* __restrict__ Wlin,  // [128][160]
                 const float* __restrict__ W1,    // [256][160]
                 const float* __restrict__ b1,    // [256]
                 const float* __restrict__ W2,    // [256][256]
                 const float* __restrict__ b2,    // [256]
                 const float* __restrict__ W3,    // [128][256]
                 const float* __restrict__ b3,    // [128]
                 u16* __restrict__ xall,          // [256][1024][128] bf16
                 float* __restrict__ out)         // xf at out[NY..]
{
  __shared__ __align__(16) char smem[SMEMB];

  const int tid  = threadIdx.x;
  const int wg   = blockIdx.x;            // batch rows wg*16..+15
  const int lane = tid & 63;
  const int v    = tid >> 6;              // wave 0..7
  const int ln   = lane & 15;             // batch index within row-group
  const int q    = lane >> 4;

  const float dt  = dtp[0];
  const float dth = 0.5f * dt;
  const float dt6 = dt * (1.0f / 6.0f);
  const f32x4 zero4 = {0.f, 0.f, 0.f, 0.f};

  // bf16 producer offset (tile pair base): byte 512*T + wby (+2r)
  const int wby = 256 * (q >> 1) + 16 * ln + 8 * (q & 1);
  // fp8 producer offsets for tiles 2v (o8a) and 2v+1 (o8b = o8a+512)
  const int o8a = 1024 * (v >> 1) + 256 * (q >> 1) + 16 * ln +
                  8 * (v & 1) + 4 * (q & 1);
  const int o8b = o8a + 512;

  // ---------------- register-resident A-fragments (weights) ----------------
  bf16x8 wc[5][2];   // W1 (bf16), h1-tiles {2v, 2v+1}
  bf16x8 wl[5];      // Wlin (bf16), lin-tile v
  long   w28[8][2];  // W2 (fp8 x 2^11), h2-tiles {2v, 2v+1}
  long   w38[8];     // W3 (fp8 x 2^11), k-tile v
#pragma unroll
  for (int kt = 0; kt < 5; kt++) {
#pragma unroll
    for (int i = 0; i < 2; i++)
      wc[kt][i] = ldw8f(W1 + (size_t)(16 * (2 * v + i) + ln) * NINQ + 32 * kt + 8 * q);
    wl[kt] = ldw8f(Wlin + (size_t)(16 * v + ln) * NINQ + 32 * kt + 8 * q);
  }
#pragma unroll
  for (int kt = 0; kt < 8; kt++) {
#pragma unroll
    for (int i = 0; i < 2; i++)
      w28[kt][i] = ldw8f8(W2 + (size_t)(16 * (2 * v + i) + ln) * NFQ + 32 * kt + 8 * q,
                          0x1p11f);
    w38[kt] = ldw8f8(W3 + (size_t)(16 * v + ln) * NFQ + 32 * kt + 8 * q, 0x1p11f);
  }

  // ---- biases in registers, pre-scaled for the fp8 pipeline ----
  f32x4 bb1s[2], bb2s[2], bb3;
#pragma unroll
  for (int i = 0; i < 2; i++) {
    f32x4 t1 = *reinterpret_cast<const f32x4*>(b1 + 16 * (2 * v + i) + 4 * q);
    f32x4 t2 = *reinterpret_cast<const f32x4*>(b2 + 16 * (2 * v + i) + 4 * q);
#pragma unroll
    for (int r = 0; r < 4; r++) {
      bb1s[i][r] = t1[r] * 0x1p9f;    // h1' = relu(a*2^9 + b1*2^9)
      bb2s[i][r] = t2[r] * 0x1p16f;   // h2' = relu(d*2^-4 + b2*2^16)
    }
  }
  bb3 = *reinterpret_cast<const f32x4*>(b3 + 16 * v + 4 * q);

  // RK4 state: xs[r] = x[batch ln][xdim 16v+4q+r]
  f32x4 xs, ksum, accl;
  xs = *reinterpret_cast<const f32x4*>(
      x0 + (size_t)(wg * 16 + ln) * NXQ + 16 * v + 4 * q);
  {
    uint2 p;
    p.x = cvtpk(xs[0], xs[1]);
    p.y = cvtpk(xs[2], xs[3]);
    *reinterpret_cast<uint2*>(smem + ZOFF + 512 * v + wby) = p;
  }
  // u B-frag (register-resident): lane holds u[ln][8q+j]
  bf16x8 uf = ldw8f(uin + (size_t)(wg * 16 + ln) * NUQ + 8 * q);
  f32x4 ur0 = zero4, ur1 = zero4;        // raw u[t+1], issued at e==0
  __syncthreads();

#pragma unroll 1
  for (int t = 0; t < TSTEPS; t++) {
#pragma unroll 1
    for (int e = 0; e < 4; e++) {
      // ---- S1 (bf16): h1-tiles {2v,2v+1} = W1 z^T ; lin-tile v in regs ----
      {
        bf16x8 zf[4];
#pragma unroll
        for (int kt = 0; kt < 4; kt++)
          zf[kt] = *reinterpret_cast<const bf16x8*>(smem + ZOFF + 1024 * kt + 16 * lane);
        f32x4 a0 = zero4, a1 = zero4, al = zero4;
#pragma unroll
        for (int kt = 0; kt < 4; kt++) {
          a0 = mfma16(wc[kt][0], zf[kt], a0);
          a1 = mfma16(wc[kt][1], zf[kt], a1);
          al = mfma16(wl[kt], zf[kt], al);
        }
        a0 = mfma16(wc[4][0], uf, a0);
        a1 = mfma16(wc[4][1], uf, a1);
        al = mfma16(wl[4], uf, al);
        accl = al;
#pragma unroll
        for (int i = 0; i < 2; i++) {
          f32x4 d = i ? a1 : a0;
          float e0 = fmaxf(fmaf(d[0], 0x1p9f, bb1s[i][0]), 0.f);
          float e1 = fmaxf(fmaf(d[1], 0x1p9f, bb1s[i][1]), 0.f);
          float e2 = fmaxf(fmaf(d[2], 0x1p9f, bb1s[i][2]), 0.f);
          float e3 = fmaxf(fmaf(d[3], 0x1p9f, bb1s[i][3]), 0.f);
          int wd = 0;
          wd = __builtin_amdgcn_cvt_pk_fp8_f32(e0, e1, wd, false);
          wd = __builtin_amdgcn_cvt_pk_fp8_f32(e2, e3, wd, true);
          *reinterpret_cast<int*>(smem + H1OFF + (i ? o8b : o8a)) = wd;
        }
      }
      bar_lds();
      // ---- S2 (fp8): h2-tiles {2v,2v+1} = W2' h1' ----
      {
        longlong2 hb[4];
#pragma unroll
        for (int p = 0; p < 4; p++)
          hb[p] = *reinterpret_cast<const longlong2*>(
              smem + H1OFF + 1024 * p + 16 * lane);
        f32x4 d0 = zero4, d1 = zero4;
#pragma unroll
        for (int p = 0; p < 4; p++) {
          d0 = mfma8(w28[2 * p][0], hb[p].x, d0);
          d1 = mfma8(w28[2 * p][1], hb[p].x, d1);
          d0 = mfma8(w28[2 * p + 1][0], hb[p].y, d0);
          d1 = mfma8(w28[2 * p + 1][1], hb[p].y, d1);
        }
#pragma unroll
        for (int i = 0; i < 2; i++) {
          f32x4 d = i ? d1 : d0;
          float e0 = fmaxf(fmaf(d[0], 0x1p-4f, bb2s[i][0]), 0.f);
          float e1 = fmaxf(fmaf(d[1], 0x1p-4f, bb2s[i][1]), 0.f);
          float e2 = fmaxf(fmaf(d[2], 0x1p-4f, bb2s[i][2]), 0.f);
          float e3 = fmaxf(fmaf(d[3], 0x1p-4f, bb2s[i][3]), 0.f);
          int wd = 0;
          wd = __builtin_amdgcn_cvt_pk_fp8_f32(e0, e1, wd, false);
          wd = __builtin_amdgcn_cvt_pk_fp8_f32(e2, e3, wd, true);
          *reinterpret_cast<int*>(smem + H2OFF + (i ? o8b : o8a)) = wd;
        }
      }
      bar_lds();
      // u[t+1]: issue raw loads early (e==0), convert late (e==3)
      if (e == 0 && t + 1 < TSTEPS) {
        const float* up = uin + ((size_t)(t + 1) * BATCH + wg * 16 + ln) * NUQ + 8 * q;
        ur0 = *reinterpret_cast<const f32x4*>(up);
        ur1 = *reinterpret_cast<const f32x4*>(up + 4);
      }
      if (e == 3 && t + 1 < TSTEPS) {
#pragma unroll
        for (int j = 0; j < 4; j++) {
          uf[j]     = (short)f2b(ur0[j]);
          uf[4 + j] = (short)f2b(ur1[j]);
        }
      }
      // ---- S3 (fp8): k-tile v = W3' h2' * 2^-27 + lin + b3 ; RK4 ----
      {
        longlong2 gb[4];
#pragma unroll
        for (int p = 0; p < 4; p++)
          gb[p] = *reinterpret_cast<const longlong2*>(
              smem + H2OFF + 1024 * p + 16 * lane);
        f32x4 ka = zero4, kb = zero4;     // two depth-4 chains
#pragma unroll
        for (int p = 0; p < 4; p++) {
          ka = mfma8(w38[2 * p], gb[p].x, ka);
          kb = mfma8(w38[2 * p + 1], gb[p].y, kb);
        }
        const float wk = (e == 1 || e == 2) ? 2.0f : 1.0f;
        const float cn = (e == 2) ? dt : dth;
        float xe[4];
#pragma unroll
        for (int r = 0; r < 4; r++) {
          float kv = fmaf(ka[r] + kb[r], 0x1p-27f, accl[r] + bb3[r]);
          if (e == 0) ksum[r] = kv; else ksum[r] += wk * kv;
          if (e == 3) { xs[r] += dt6 * ksum[r]; xe[r] = xs[r]; }
          else        { xe[r] = xs[r] + cn * kv; }
        }
        uint2 p;
        p.x = cvtpk(xe[0], xe[1]);
        p.y = cvtpk(xe[2], xe[3]);
        *reinterpret_cast<uint2*>(smem + ZOFF + 512 * v + wby) = p;
        if (e == 3)
          *reinterpret_cast<uint2*>(
              xall + ((size_t)t * BATCH + wg * 16 + ln) * NXQ + 16 * v + 4 * q) = p;
      }
      bar_lds();
    }
  }

  // x_final (f32), vectorized
  *reinterpret_cast<f32x4*>(
      out + NY + (size_t)(wg * 16 + ln) * NXQ + 16 * v + 4 * q) = xs;
}

// ======================= Phase 2: bulk out_net GEMM =========================
// Processes y rows [16*slab .. ) for slabs in [slab0+blk*spw, slab_end).
__global__ __launch_bounds__(512, 2)
void outnet_kernel(const u16* __restrict__ xall,  // [rows][128] bf16
                   const float* __restrict__ Wo1, const float* __restrict__ bo1,
                   const float* __restrict__ Wo2, const float* __restrict__ bo2,
                   const float* __restrict__ Wo3, const float* __restrict__ bo3,
                   float* __restrict__ out,       // y [rows][128] f32
                   int slab0, int slab_end, int spw)
{
  __shared__ u16 h1[2][16][264];
  __shared__ u16 h2[2][16][264];

  const int tid  = threadIdx.x;
  const int lane = tid & 63;
  const int v    = tid >> 6;
  const int ln   = lane & 15;
  const int q    = lane >> 4;
  const int n1   = 16 * v + ln;
  const int n2   = 128 + n1;
  const f32x4 zero4 = {0.f, 0.f, 0.f, 0.f};

  bf16x8 f1[4][2];
#pragma unroll
  for (int kt = 0; kt < 4; kt++) {
    int k = 32 * kt + 8 * q;
    f1[kt][0] = ldw8f(Wo1 + n1 * NXQ + k);
    f1[kt][1] = ldw8f(Wo1 + n2 * NXQ + k);
  }
  bf16x8 f2[8][2];
#pragma unroll
  for (int kt = 0; kt < 8; kt++) {
    int k = 32 * kt + 8 * q;
    f2[kt][0] = ldw8f(Wo2 + n1 * NFQ + k);
    f2[kt][1] = ldw8f(Wo2 + n2 * NFQ + k);
  }
  bf16x8 f3[8];
#pragma unroll
  for (int kt = 0; kt < 8; kt++)
    f3[kt] = ldw8f(Wo3 + n1 * NFQ + 32 * kt + 8 * q);

  const float c1a = bo1[n1], c1b = bo1[n2];
  const float c2a = bo2[n1], c2b = bo2[n2];
  const float c3  = bo3[n1];

  const int s0  = slab0 + (int)blockIdx.x * spw;
  int cnt = slab_end - s0; if (cnt > spw) cnt = spw;
  if (cnt <= 0) return;

  bf16x8 a[4], an[4];
#pragma unroll
  for (int kt = 0; kt < 4; kt++)
    a[kt] = *reinterpret_cast<const bf16x8*>(
        &xall[((size_t)16 * s0 + ln) * NXQ + 32 * kt + 8 * q]);

#pragma unroll 1
  for (int i = 0; i < cnt; i++) {
    const int s = s0 + i, par = i & 1;
    if (i + 1 < cnt) {
#pragma unroll
      for (int kt = 0; kt < 4; kt++)
        an[kt] = *reinterpret_cast<const bf16x8*>(
            &xall[((size_t)16 * (s + 1) + ln) * NXQ + 32 * kt + 8 * q]);
    }
    // o1
    {
      f32x4 d0 = zero4, d1 = zero4;
#pragma unroll
      for (int kt = 0; kt < 4; kt++) {
        d0 = mfma16(a[kt], f1[kt][0], d0);
        d1 = mfma16(a[kt], f1[kt][1], d1);
      }
#pragma unroll
      for (int r = 0; r < 4; r++) {
        h1[par][4 * q + r][n1] = f2b(fmaxf(d0[r] + c1a, 0.f));
        h1[par][4 * q + r][n2] = f2b(fmaxf(d1[r] + c1b, 0.f));
      }
    }
    __syncthreads();
    // o2
    {
      bf16x8 c[8];
#pragma unroll
      for (int kt = 0; kt < 8; kt++)
        c[kt] = *reinterpret_cast<const bf16x8*>(&h1[par][ln][32 * kt + 8 * q]);
      f32x4 e0 = zero4, e1 = zero4;
#pragma unroll
      for (int kt = 0; kt < 8; kt++) {
        e0 = mfma16(c[kt], f2[kt][0], e0);
        e1 = mfma16(c[kt], f2[kt][1], e1);
      }
#pragma unroll
      for (int r = 0; r < 4; r++) {
        h2[par][4 * q + r][n1] = f2b(fmaxf(e0[r] + c2a, 0.f));
        h2[par][4 * q + r][n2] = f2b(fmaxf(e1[r] + c2b, 0.f));
      }
    }
    __syncthreads();
    // o3 -> y (f32); no trailing barrier (ping-pong buffers)
    {
      bf16x8 g[8];
#pragma unroll
      for (int kt = 0; kt < 8; kt++)
        g[kt] = *reinterpret_cast<const bf16x8*>(&h2[par][ln][32 * kt + 8 * q]);
      f32x4 y = zero4;
#pragma unroll
      for (int kt = 0; kt < 8; kt++) y = mfma16(g[kt], f3[kt], y);
#pragma unroll
      for (int r = 0; r < 4; r++)
        out[((size_t)16 * s + 4 * q + r) * NXQ + n1] = y[r] + c3;
    }
#pragma unroll
    for (int kt = 0; kt < 4; kt++) a[kt] = an[kt];
  }
}

extern "C" void kernel_launch(void* const* d_in, const int* in_sizes, int n_in,
                              void* d_out, int out_size, void* d_ws, size_t ws_size,
                              hipStream_t stream) {
  const float* uin  = (const float*)d_in[0];
  const float* x0   = (const float*)d_in[1];
  const float* dtp  = (const float*)d_in[2];
  const float* Wlin = (const float*)d_in[3];
  const float* W1   = (const float*)d_in[4];
  const float* b1   = (const float*)d_in[5];
  const float* W2   = (const float*)d_in[6];
  const float* b2   = (const float*)d_in[7];
  const float* W3   = (const float*)d_in[8];
  const float* b3   = (const float*)d_in[9];
  const float* Wo1  = (const float*)d_in[10];
  const float* bo1  = (const float*)d_in[11];
  const float* Wo2  = (const float*)d_in[12];
  const float* bo2  = (const float*)d_in[13];
  const float* Wo3  = (const float*)d_in[14];
  const float* bo3  = (const float*)d_in[15];
  float* out = (float*)d_out;

  const size_t xall_bytes = NY * sizeof(u16);   // 64 MiB
  const bool ws_ok = (ws_size >= xall_bytes);
  u16* xall = ws_ok ? (u16*)d_ws : (u16*)d_out;  // fallback: front of y region

  scan_kernel<<<dim3(64), dim3(512), 0, stream>>>(
      uin, x0, dtp, Wlin, W1, b1, W2, b2, W3, b3, xall, out);

  const int nslab = TSTEPS * BATCH / 16;        // 16384
  if (ws_ok) {
    const int spw = 32;
    outnet_kernel<<<dim3(nslab / spw), dim3(512), 0, stream>>>(
        xall, Wo1, bo1, Wo2, bo2, Wo3, bo3, out, 0, nslab, spw);
  } else {
    // y[slab s] overwrites x-slabs [2s,2s+2): process [S,2S) in halving
    // passes so clobbered x-slabs are always already consumed.
    for (int S = nslab / 2; S >= 1; S >>= 1) {
      int grid = S < 512 ? S : 512;
      int spw  = (S + grid - 1) / grid;
      outnet_kernel<<<dim3(grid), dim3(512), 0, stream>>>(
          xall, Wo1, bo1, Wo2, bo2, Wo3, bo3, out, S, 2 * S, spw);
    }
    outnet_kernel<<<dim3(1), dim3(512), 0, stream>>>(
        xall, Wo1, bo1, Wo2, bo2, Wo3, bo3, out, 0, 1, 1);
  }
}

// Round 7
// 1280.697 us; speedup vs baseline: 1.6069x; 1.0775x over previous
//
#include <hip/hip_runtime.h>

// ODELayer RK4 scan — R10 "MX-scaled fp8 K=128 for S2/S3" (resubmit; R6's
// bench failed at container level with no kernel diagnostic — infra flake).
//   R9 (1152 µs scan) left per-eval = MFMA floor 1513 cyc + ~1200 exposure.
//   R10 shrinks the floor: S2/S3 use mfma_scale_f32_16x16x128_f8f6f4
//   (K=128, 2.25x bf16 FLOP rate) with scale operands = 1.0 (e8m0 127).
//   Arithmetic identical to R9's fp8 path (same e4m3 bytes, same 2^11 /
//   2^9 / 2^16 power-of-2 scales, f32 accumulate) — only K-grouping of
//   the accumulation changes. S2: 16->4 instrs/wave; S3: 8->2.
//   h1/h2 LDS layout: byte(k,n) = 512*(k>>5) + 32*n + (k&31); producer
//   writes one b32 per tile at 512*v + 32*ln + 4*q (+16 for odd tile);
//   consumer lane reads 32 contiguous bytes (2-way bank alias = free).
//   S1 (K=160 lin path, accuracy-critical) stays bf16. Barriers stay
//   lgkmcnt-only. Phase 2 (outnet_kernel) unchanged.

#define TSTEPS 256
#define BATCH  1024
#define NUQ    32
#define NXQ    128
#define NFQ    256
#define NINQ   160
#define NY     ((size_t)TSTEPS * BATCH * NXQ)

typedef __attribute__((ext_vector_type(8))) short bf16x8;
typedef __attribute__((ext_vector_type(4))) short s16x4;
typedef __attribute__((ext_vector_type(4))) float f32x4;
typedef __attribute__((ext_vector_type(8))) int i32x8;
typedef __attribute__((ext_vector_type(4))) int i32x4;
typedef unsigned short u16;

__device__ __forceinline__ u16 f2b(float f) {
  unsigned u = __float_as_uint(f);
  u = (u + 0x7FFFu + ((u >> 16) & 1u)) >> 16;
  return (u16)u;
}
__device__ __forceinline__ unsigned cvtpk(float a, float b) {
  unsigned r;
  asm("v_cvt_pk_bf16_f32 %0, %1, %2" : "=v"(r) : "v"(a), "v"(b));
  return r;
}
__device__ __forceinline__ f32x4 mfma16(bf16x8 a, bf16x8 b, f32x4 c) {
  return __builtin_amdgcn_mfma_f32_16x16x32_bf16(a, b, c, 0, 0, 0);
}
// MX-scaled fp8 MFMA, K=128, scales = 1.0 (e8m0 byte 127 in every slot).
__device__ __forceinline__ f32x4 mfmx(i32x8 a, i32x8 b, f32x4 c) {
  return __builtin_amdgcn_mfma_scale_f32_16x16x128_f8f6f4(
      a, b, c, 0, 0, 0, 0x7F7F7F7F, 0, 0x7F7F7F7F);
}
// 8 consecutive f32 weights -> bf16 fragment (16B-aligned source).
__device__ __forceinline__ bf16x8 ldw8f(const float* p) {
  f32x4 a = *reinterpret_cast<const f32x4*>(p);
  f32x4 b = *reinterpret_cast<const f32x4*>(p + 4);
  bf16x8 r;
  r[0] = (short)f2b(a[0]); r[1] = (short)f2b(a[1]);
  r[2] = (short)f2b(a[2]); r[3] = (short)f2b(a[3]);
  r[4] = (short)f2b(b[0]); r[5] = (short)f2b(b[1]);
  r[6] = (short)f2b(b[2]); r[7] = (short)f2b(b[3]);
  return r;
}
// 32 consecutive f32 weights -> 32 scaled fp8 e4m3 bytes (i32x8).
__device__ __forceinline__ i32x8 ldw32f8(const float* p, float s) {
  i32x8 r;
#pragma unroll
  for (int j = 0; j < 8; j++) {
    f32x4 a = *reinterpret_cast<const f32x4*>(p + 4 * j);
    int wd = 0;
    wd = __builtin_amdgcn_cvt_pk_fp8_f32(a[0] * s, a[1] * s, wd, false);
    wd = __builtin_amdgcn_cvt_pk_fp8_f32(a[2] * s, a[3] * s, wd, true);
    r[j] = wd;
  }
  return r;
}
// LDS-only barrier: no vmcnt drain (no cross-wave global-memory consumers).
__device__ __forceinline__ void bar_lds() {
  asm volatile("s_waitcnt lgkmcnt(0)" ::: "memory");
  __builtin_amdgcn_s_barrier();
  asm volatile("" ::: "memory");
}

// LDS map:
//  z  (bf16): 4 frags x 1KB at ZOFF (16*lane within frag; tile T at frag
//             T>>1, half T&1; producer byte 512*T + wby).
//  h1,h2 (fp8, MX layout): byte(k,n) = 512*(k>>5) + 32n + (k&31); 4KB each.
#define ZOFF  0
#define H1OFF 4096
#define H2OFF 8192
#define SMEMB 12288

// ======================= Phase 1: the sequential scan =======================
__global__ __launch_bounds__(512, 2)
void scan_kernel(const float* __restrict__ uin,   // [256][1024][32]
                 const float* __restrict__ x0,    // [1024][128]
                 const float* __restrict__ dtp,
                 const float* __restrict__ Wlin,  // [128][160]
                 const float* __restrict__ W1,    // [256][160]
                 const float* __restrict__ b1,    // [256]
                 const float* __restrict__ W2,    // [256][256]
                 const float* __restrict__ b2,    // [256]
                 const float* __restrict__ W3,    // [128][256]
                 const float* __restrict__ b3,    // [128]
                 u16* __restrict__ xall,          // [256][1024][128] bf16
                 float* __restrict__ out)         // xf at out[NY..]
{
  __shared__ __align__(16) char smem[SMEMB];

  const int tid  = threadIdx.x;
  const int wg   = blockIdx.x;            // batch rows wg*16..+15
  const int lane = tid & 63;
  const int v    = tid >> 6;              // wave 0..7
  const int ln   = lane & 15;             // batch index within row-group
  const int q    = lane >> 4;

  const float dt  = dtp[0];
  const float dth = 0.5f * dt;
  const float dt6 = dt * (1.0f / 6.0f);
  const f32x4 zero4 = {0.f, 0.f, 0.f, 0.f};

  // bf16 z producer offset (tile pair base): byte 512*T + wby (+2r)
  const int wby = 256 * (q >> 1) + 16 * ln + 8 * (q & 1);
  // fp8 MX producer offsets: tile 2v at o8a, tile 2v+1 at o8a+16
  const int o8a = 512 * v + 32 * ln + 4 * q;
  const int o8b = o8a + 16;
  // fp8 MX consumer base (lane's 32B row within a K=128 block)
  const int rb  = 512 * q + 32 * ln;

  // ---------------- register-resident A-fragments (weights) ----------------
  bf16x8 wc[5][2];   // W1 (bf16), h1-tiles {2v, 2v+1}
  bf16x8 wl[5];      // Wlin (bf16), lin-tile v
  i32x8  w2x[2][2];  // W2 (fp8 x 2^11), [K-block b][tile i]
  i32x8  w3x[2];     // W3 (fp8 x 2^11), [K-block b], k-tile v
#pragma unroll
  for (int kt = 0; kt < 5; kt++) {
#pragma unroll
    for (int i = 0; i < 2; i++)
      wc[kt][i] = ldw8f(W1 + (size_t)(16 * (2 * v + i) + ln) * NINQ + 32 * kt + 8 * q);
    wl[kt] = ldw8f(Wlin + (size_t)(16 * v + ln) * NINQ + 32 * kt + 8 * q);
  }
#pragma unroll
  for (int b = 0; b < 2; b++) {
#pragma unroll
    for (int i = 0; i < 2; i++)
      w2x[b][i] = ldw32f8(W2 + (size_t)(16 * (2 * v + i) + ln) * NFQ + 128 * b + 32 * q,
                          0x1p11f);
    w3x[b] = ldw32f8(W3 + (size_t)(16 * v + ln) * NFQ + 128 * b + 32 * q, 0x1p11f);
  }

  // ---- biases in registers, pre-scaled for the fp8 pipeline ----
  f32x4 bb1s[2], bb2s[2], bb3;
#pragma unroll
  for (int i = 0; i < 2; i++) {
    f32x4 t1 = *reinterpret_cast<const f32x4*>(b1 + 16 * (2 * v + i) + 4 * q);
    f32x4 t2 = *reinterpret_cast<const f32x4*>(b2 + 16 * (2 * v + i) + 4 * q);
#pragma unroll
    for (int r = 0; r < 4; r++) {
      bb1s[i][r] = t1[r] * 0x1p9f;    // h1' = relu(a*2^9 + b1*2^9)
      bb2s[i][r] = t2[r] * 0x1p16f;   // h2' = relu(d*2^-4 + b2*2^16)
    }
  }
  bb3 = *reinterpret_cast<const f32x4*>(b3 + 16 * v + 4 * q);

  // RK4 state: xs[r] = x[batch ln][xdim 16v+4q+r]
  f32x4 xs, ksum, accl;
  xs = *reinterpret_cast<const f32x4*>(
      x0 + (size_t)(wg * 16 + ln) * NXQ + 16 * v + 4 * q);
  {
    uint2 p;
    p.x = cvtpk(xs[0], xs[1]);
    p.y = cvtpk(xs[2], xs[3]);
    *reinterpret_cast<uint2*>(smem + ZOFF + 512 * v + wby) = p;
  }
  // u B-frag (register-resident): lane holds u[ln][8q+j]
  bf16x8 uf = ldw8f(uin + (size_t)(wg * 16 + ln) * NUQ + 8 * q);
  f32x4 ur0 = zero4, ur1 = zero4;        // raw u[t+1], issued at e==0
  __syncthreads();

#pragma unroll 1
  for (int t = 0; t < TSTEPS; t++) {
#pragma unroll 1
    for (int e = 0; e < 4; e++) {
      // ---- S1 (bf16): h1-tiles {2v,2v+1} = W1 z^T ; lin-tile v in regs ----
      {
        bf16x8 zf[4];
#pragma unroll
        for (int kt = 0; kt < 4; kt++)
          zf[kt] = *reinterpret_cast<const bf16x8*>(smem + ZOFF + 1024 * kt + 16 * lane);
        f32x4 a0 = zero4, a1 = zero4, al = zero4;
#pragma unroll
        for (int kt = 0; kt < 4; kt++) {
          a0 = mfma16(wc[kt][0], zf[kt], a0);
          a1 = mfma16(wc[kt][1], zf[kt], a1);
          al = mfma16(wl[kt], zf[kt], al);
        }
        a0 = mfma16(wc[4][0], uf, a0);
        a1 = mfma16(wc[4][1], uf, a1);
        al = mfma16(wl[4], uf, al);
        accl = al;
#pragma unroll
        for (int i = 0; i < 2; i++) {
          f32x4 d = i ? a1 : a0;
          float e0 = fmaxf(fmaf(d[0], 0x1p9f, bb1s[i][0]), 0.f);
          float e1 = fmaxf(fmaf(d[1], 0x1p9f, bb1s[i][1]), 0.f);
          float e2 = fmaxf(fmaf(d[2], 0x1p9f, bb1s[i][2]), 0.f);
          float e3 = fmaxf(fmaf(d[3], 0x1p9f, bb1s[i][3]), 0.f);
          int wd = 0;
          wd = __builtin_amdgcn_cvt_pk_fp8_f32(e0, e1, wd, false);
          wd = __builtin_amdgcn_cvt_pk_fp8_f32(e2, e3, wd, true);
          *reinterpret_cast<int*>(smem + H1OFF + (i ? o8b : o8a)) = wd;
        }
      }
      bar_lds();
      // ---- S2 (MX fp8 K=128): h2-tiles {2v,2v+1} = W2' h1' ----
      {
        i32x4 l0 = *reinterpret_cast<const i32x4*>(smem + H1OFF + rb);
        i32x4 l1 = *reinterpret_cast<const i32x4*>(smem + H1OFF + rb + 16);
        i32x4 l2 = *reinterpret_cast<const i32x4*>(smem + H1OFF + 2048 + rb);
        i32x4 l3 = *reinterpret_cast<const i32x4*>(smem + H1OFF + 2048 + rb + 16);
        i32x8 hb0 = {l0[0], l0[1], l0[2], l0[3], l1[0], l1[1], l1[2], l1[3]};
        i32x8 hb1 = {l2[0], l2[1], l2[2], l2[3], l3[0], l3[1], l3[2], l3[3]};
        f32x4 d0 = mfmx(w2x[0][0], hb0, zero4);
        f32x4 d1 = mfmx(w2x[0][1], hb0, zero4);
        d0 = mfmx(w2x[1][0], hb1, d0);
        d1 = mfmx(w2x[1][1], hb1, d1);
#pragma unroll
        for (int i = 0; i < 2; i++) {
          f32x4 d = i ? d1 : d0;
          float e0 = fmaxf(fmaf(d[0], 0x1p-4f, bb2s[i][0]), 0.f);
          float e1 = fmaxf(fmaf(d[1], 0x1p-4f, bb2s[i][1]), 0.f);
          float e2 = fmaxf(fmaf(d[2], 0x1p-4f, bb2s[i][2]), 0.f);
          float e3 = fmaxf(fmaf(d[3], 0x1p-4f, bb2s[i][3]), 0.f);
          int wd = 0;
          wd = __builtin_amdgcn_cvt_pk_fp8_f32(e0, e1, wd, false);
          wd = __builtin_amdgcn_cvt_pk_fp8_f32(e2, e3, wd, true);
          *reinterpret_cast<int*>(smem + H2OFF + (i ? o8b : o8a)) = wd;
        }
      }
      bar_lds();
      // u[t+1]: issue raw loads early (e==0), convert late (e==3)
      if (e == 0 && t + 1 < TSTEPS) {
        const float* up = uin + ((size_t)(t + 1) * BATCH + wg * 16 + ln) * NUQ + 8 * q;
        ur0 = *reinterpret_cast<const f32x4*>(up);
        ur1 = *reinterpret_cast<const f32x4*>(up + 4);
      }
      if (e == 3 && t + 1 < TSTEPS) {
#pragma unroll
        for (int j = 0; j < 4; j++) {
          uf[j]     = (short)f2b(ur0[j]);
          uf[4 + j] = (short)f2b(ur1[j]);
        }
      }
      // ---- S3 (MX fp8 K=128): k-tile v = W3' h2' * 2^-27 + lin + b3 ----
      {
        i32x4 l0 = *reinterpret_cast<const i32x4*>(smem + H2OFF + rb);
        i32x4 l1 = *reinterpret_cast<const i32x4*>(smem + H2OFF + rb + 16);
        i32x4 l2 = *reinterpret_cast<const i32x4*>(smem + H2OFF + 2048 + rb);
        i32x4 l3 = *reinterpret_cast<const i32x4*>(smem + H2OFF + 2048 + rb + 16);
        i32x8 gb0 = {l0[0], l0[1], l0[2], l0[3], l1[0], l1[1], l1[2], l1[3]};
        i32x8 gb1 = {l2[0], l2[1], l2[2], l2[3], l3[0], l3[1], l3[2], l3[3]};
        f32x4 ka = mfmx(w3x[0], gb0, zero4);
        ka = mfmx(w3x[1], gb1, ka);
        const float wk = (e == 1 || e == 2) ? 2.0f : 1.0f;
        const float cn = (e == 2) ? dt : dth;
        float xe[4];
#pragma unroll
        for (int r = 0; r < 4; r++) {
          float kv = fmaf(ka[r], 0x1p-27f, accl[r] + bb3[r]);
          if (e == 0) ksum[r] = kv; else ksum[r] += wk * kv;
          if (e == 3) { xs[r] += dt6 * ksum[r]; xe[r] = xs[r]; }
          else        { xe[r] = xs[r] + cn * kv; }
        }
        uint2 p;
        p.x = cvtpk(xe[0], xe[1]);
        p.y = cvtpk(xe[2], xe[3]);
        *reinterpret_cast<uint2*>(smem + ZOFF + 512 * v + wby) = p;
        if (e == 3)
          *reinterpret_cast<uint2*>(
              xall + ((size_t)t * BATCH + wg * 16 + ln) * NXQ + 16 * v + 4 * q) = p;
      }
      bar_lds();
    }
  }

  // x_final (f32), vectorized
  *reinterpret_cast<f32x4*>(
      out + NY + (size_t)(wg * 16 + ln) * NXQ + 16 * v + 4 * q) = xs;
}

// ======================= Phase 2: bulk out_net GEMM =========================
// Processes y rows [16*slab .. ) for slabs in [slab0+blk*spw, slab_end).
__global__ __launch_bounds__(512, 2)
void outnet_kernel(const u16* __restrict__ xall,  // [rows][128] bf16
                   const float* __restrict__ Wo1, const float* __restrict__ bo1,
                   const float* __restrict__ Wo2, const float* __restrict__ bo2,
                   const float* __restrict__ Wo3, const float* __restrict__ bo3,
                   float* __restrict__ out,       // y [rows][128] f32
                   int slab0, int slab_end, int spw)
{
  __shared__ u16 h1[2][16][264];
  __shared__ u16 h2[2][16][264];

  const int tid  = threadIdx.x;
  const int lane = tid & 63;
  const int v    = tid >> 6;
  const int ln   = lane & 15;
  const int q    = lane >> 4;
  const int n1   = 16 * v + ln;
  const int n2   = 128 + n1;
  const f32x4 zero4 = {0.f, 0.f, 0.f, 0.f};

  bf16x8 f1[4][2];
#pragma unroll
  for (int kt = 0; kt < 4; kt++) {
    int k = 32 * kt + 8 * q;
    f1[kt][0] = ldw8f(Wo1 + n1 * NXQ + k);
    f1[kt][1] = ldw8f(Wo1 + n2 * NXQ + k);
  }
  bf16x8 f2[8][2];
#pragma unroll
  for (int kt = 0; kt < 8; kt++) {
    int k = 32 * kt + 8 * q;
    f2[kt][0] = ldw8f(Wo2 + n1 * NFQ + k);
    f2[kt][1] = ldw8f(Wo2 + n2 * NFQ + k);
  }
  bf16x8 f3[8];
#pragma unroll
  for (int kt = 0; kt < 8; kt++)
    f3[kt] = ldw8f(Wo3 + n1 * NFQ + 32 * kt + 8 * q);

  const float c1a = bo1[n1], c1b = bo1[n2];
  const float c2a = bo2[n1], c2b = bo2[n2];
  const float c3  = bo3[n1];

  const int s0  = slab0 + (int)blockIdx.x * spw;
  int cnt = slab_end - s0; if (cnt > spw) cnt = spw;
  if (cnt <= 0) return;

  bf16x8 a[4], an[4];
#pragma unroll
  for (int kt = 0; kt < 4; kt++)
    a[kt] = *reinterpret_cast<const bf16x8*>(
        &xall[((size_t)16 * s0 + ln) * NXQ + 32 * kt + 8 * q]);

#pragma unroll 1
  for (int i = 0; i < cnt; i++) {
    const int s = s0 + i, par = i & 1;
    if (i + 1 < cnt) {
#pragma unroll
      for (int kt = 0; kt < 4; kt++)
        an[kt] = *reinterpret_cast<const bf16x8*>(
            &xall[((size_t)16 * (s + 1) + ln) * NXQ + 32 * kt + 8 * q]);
    }
    // o1
    {
      f32x4 d0 = zero4, d1 = zero4;
#pragma unroll
      for (int kt = 0; kt < 4; kt++) {
        d0 = mfma16(a[kt], f1[kt][0], d0);
        d1 = mfma16(a[kt], f1[kt][1], d1);
      }
#pragma unroll
      for (int r = 0; r < 4; r++) {
        h1[par][4 * q + r][n1] = f2b(fmaxf(d0[r] + c1a, 0.f));
        h1[par][4 * q + r][n2] = f2b(fmaxf(d1[r] + c1b, 0.f));
      }
    }
    __syncthreads();
    // o2
    {
      bf16x8 c[8];
#pragma unroll
      for (int kt = 0; kt < 8; kt++)
        c[kt] = *reinterpret_cast<const bf16x8*>(&h1[par][ln][32 * kt + 8 * q]);
      f32x4 e0 = zero4, e1 = zero4;
#pragma unroll
      for (int kt = 0; kt < 8; kt++) {
        e0 = mfma16(c[kt], f2[kt][0], e0);
        e1 = mfma16(c[kt], f2[kt][1], e1);
      }
#pragma unroll
      for (int r = 0; r < 4; r++) {
        h2[par][4 * q + r][n1] = f2b(fmaxf(e0[r] + c2a, 0.f));
        h2[par][4 * q + r][n2] = f2b(fmaxf(e1[r] + c2b, 0.f));
      }
    }
    __syncthreads();
    // o3 -> y (f32); no trailing barrier (ping-pong buffers)
    {
      bf16x8 g[8];
#pragma unroll
      for (int kt = 0; kt < 8; kt++)
        g[kt] = *reinterpret_cast<const bf16x8*>(&h2[par][ln][32 * kt + 8 * q]);
      f32x4 y = zero4;
#pragma unroll
      for (int kt = 0; kt < 8; kt++) y = mfma16(g[kt], f3[kt], y);
#pragma unroll
      for (int r = 0; r < 4; r++)
        out[((size_t)16 * s + 4 * q + r) * NXQ + n1] = y[r] + c3;
    }
#pragma unroll
    for (int kt = 0; kt < 4; kt++) a[kt] = an[kt];
  }
}

extern "C" void kernel_launch(void* const* d_in, const int* in_sizes, int n_in,
                              void* d_out, int out_size, void* d_ws, size_t ws_size,
                              hipStream_t stream) {
  const float* uin  = (const float*)d_in[0];
  const float* x0   = (const float*)d_in[1];
  const float* dtp  = (const float*)d_in[2];
  const float* Wlin = (const float*)d_in[3];
  const float* W1   = (const float*)d_in[4];
  const float* b1   = (const float*)d_in[5];
  const float* W2   = (const float*)d_in[6];
  const float* b2   = (const float*)d_in[7];
  const float* W3   = (const float*)d_in[8];
  const float* b3   = (const float*)d_in[9];
  const float* Wo1  = (const float*)d_in[10];
  const float* bo1  = (const float*)d_in[11];
  const float* Wo2  = (const float*)d_in[12];
  const float* bo2  = (const float*)d_in[13];
  const float* Wo3  = (const float*)d_in[14];
  const float* bo3  = (const float*)d_in[15];
  float* out = (float*)d_out;

  const size_t xall_bytes = NY * sizeof(u16);   // 64 MiB
  const bool ws_ok = (ws_size >= xall_bytes);
  u16* xall = ws_ok ? (u16*)d_ws : (u16*)d_out;  // fallback: front of y region

  scan_kernel<<<dim3(64), dim3(512), 0, stream>>>(
      uin, x0, dtp, Wlin, W1, b1, W2, b2, W3, b3, xall, out);

  const int nslab = TSTEPS * BATCH / 16;        // 16384
  if (ws_ok) {
    const int spw = 32;
    outnet_kernel<<<dim3(nslab / spw), dim3(512), 0, stream>>>(
        xall, Wo1, bo1, Wo2, bo2, Wo3, bo3, out, 0, nslab, spw);
  } else {
    // y[slab s] overwrites x-slabs [2s,2s+2): process [S,2S) in halving
    // passes so clobbered x-slabs are always already consumed.
    for (int S = nslab / 2; S >= 1; S >>= 1) {
      int grid = S < 512 ? S : 512;
      int spw  = (S + grid - 1) / grid;
      outnet_kernel<<<dim3(grid), dim3(512), 0, stream>>>(
          xall, Wo1, bo1, Wo2, bo2, Wo3, bo3, out, S, 2 * S, spw);
    }
    outnet_kernel<<<dim3(1), dim3(512), 0, stream>>>(
        xall, Wo1, bo1, Wo2, bo2, Wo3, bo3, out, 0, 1, 1);
  }
}

// Round 8
// 1265.855 us; speedup vs baseline: 1.6258x; 1.0117x over previous
//
#include <hip/hip_runtime.h>

// ODELayer RK4 scan — R11 "R10 + XOR-swizzled MX h-buffers".
//   R10 (1050 µs scan) counters: SQ_LDS_BANK_CONFLICT 5x'd to 3.15e7 —
//   the MX consumer b128 reads at 512q+32ln hit only EVEN 16B-slots
//   (slot=(2ln)&7) -> 4-way conflict in each 16-lane phase (~480 cyc/eval).
//   Fix (T2 adapted): swizzle byte ^= ((ln>>2)&3)<<4 on BOTH producer and
//   consumer sides (bits 0-3 untouched -> producer b32 chunks intact).
//   Slot maps verified: consumer and producer both become 2-way (free).
//   Bytes/arithmetic identical -> absmax must stay 0.015625.
//   Everything else = R10: S2/S3 MX-scaled fp8 K=128 (scales=1.0), S1 bf16,
//   lgkmcnt-only barriers. Phase 2 (outnet_kernel) unchanged.

#define TSTEPS 256
#define BATCH  1024
#define NUQ    32
#define NXQ    128
#define NFQ    256
#define NINQ   160
#define NY     ((size_t)TSTEPS * BATCH * NXQ)

typedef __attribute__((ext_vector_type(8))) short bf16x8;
typedef __attribute__((ext_vector_type(4))) short s16x4;
typedef __attribute__((ext_vector_type(4))) float f32x4;
typedef __attribute__((ext_vector_type(8))) int i32x8;
typedef __attribute__((ext_vector_type(4))) int i32x4;
typedef unsigned short u16;

__device__ __forceinline__ u16 f2b(float f) {
  unsigned u = __float_as_uint(f);
  u = (u + 0x7FFFu + ((u >> 16) & 1u)) >> 16;
  return (u16)u;
}
__device__ __forceinline__ unsigned cvtpk(float a, float b) {
  unsigned r;
  asm("v_cvt_pk_bf16_f32 %0, %1, %2" : "=v"(r) : "v"(a), "v"(b));
  return r;
}
__device__ __forceinline__ f32x4 mfma16(bf16x8 a, bf16x8 b, f32x4 c) {
  return __builtin_amdgcn_mfma_f32_16x16x32_bf16(a, b, c, 0, 0, 0);
}
// MX-scaled fp8 MFMA, K=128, scales = 1.0 (e8m0 byte 127 in every slot).
__device__ __forceinline__ f32x4 mfmx(i32x8 a, i32x8 b, f32x4 c) {
  return __builtin_amdgcn_mfma_scale_f32_16x16x128_f8f6f4(
      a, b, c, 0, 0, 0, 0x7F7F7F7F, 0, 0x7F7F7F7F);
}
// 8 consecutive f32 weights -> bf16 fragment (16B-aligned source).
__device__ __forceinline__ bf16x8 ldw8f(const float* p) {
  f32x4 a = *reinterpret_cast<const f32x4*>(p);
  f32x4 b = *reinterpret_cast<const f32x4*>(p + 4);
  bf16x8 r;
  r[0] = (short)f2b(a[0]); r[1] = (short)f2b(a[1]);
  r[2] = (short)f2b(a[2]); r[3] = (short)f2b(a[3]);
  r[4] = (short)f2b(b[0]); r[5] = (short)f2b(b[1]);
  r[6] = (short)f2b(b[2]); r[7] = (short)f2b(b[3]);
  return r;
}
// 32 consecutive f32 weights -> 32 scaled fp8 e4m3 bytes (i32x8).
__device__ __forceinline__ i32x8 ldw32f8(const float* p, float s) {
  i32x8 r;
#pragma unroll
  for (int j = 0; j < 8; j++) {
    f32x4 a = *reinterpret_cast<const f32x4*>(p + 4 * j);
    int wd = 0;
    wd = __builtin_amdgcn_cvt_pk_fp8_f32(a[0] * s, a[1] * s, wd, false);
    wd = __builtin_amdgcn_cvt_pk_fp8_f32(a[2] * s, a[3] * s, wd, true);
    r[j] = wd;
  }
  return r;
}
// LDS-only barrier: no vmcnt drain (no cross-wave global-memory consumers).
__device__ __forceinline__ void bar_lds() {
  asm volatile("s_waitcnt lgkmcnt(0)" ::: "memory");
  __builtin_amdgcn_s_barrier();
  asm volatile("" ::: "memory");
}

// LDS map:
//  z  (bf16): 4 frags x 1KB at ZOFF (16*lane within frag; tile T at frag
//             T>>1, half T&1; producer byte 512*T + wby).
//  h1,h2 (fp8, MX layout, swizzled): byte(k,n) =
//       (512*(k>>5) + 32*n + (k&31)) ^ (((n>>2)&3)<<4); 4KB each.
#define ZOFF  0
#define H1OFF 4096
#define H2OFF 8192
#define SMEMB 12288

// ======================= Phase 1: the sequential scan =======================
__global__ __launch_bounds__(512, 2)
void scan_kernel(const float* __restrict__ uin,   // [256][1024][32]
                 const float* __restrict__ x0,    // [1024][128]
                 const float* __restrict__ dtp,
                 const float* __restrict__ Wlin,  // [128][160]
                 const float* __restrict__ W1,    // [256][160]
                 const float* __restrict__ b1,    // [256]
                 const float* __restrict__ W2,    // [256][256]
                 const float* __restrict__ b2,    // [256]
                 const float* __restrict__ W3,    // [128][256]
                 const float* __restrict__ b3,    // [128]
                 u16* __restrict__ xall,          // [256][1024][128] bf16
                 float* __restrict__ out)         // xf at out[NY..]
{
  __shared__ __align__(16) char smem[SMEMB];

  const int tid  = threadIdx.x;
  const int wg   = blockIdx.x;            // batch rows wg*16..+15
  const int lane = tid & 63;
  const int v    = tid >> 6;              // wave 0..7
  const int ln   = lane & 15;             // batch index within row-group
  const int q    = lane >> 4;

  const float dt  = dtp[0];
  const float dth = 0.5f * dt;
  const float dt6 = dt * (1.0f / 6.0f);
  const f32x4 zero4 = {0.f, 0.f, 0.f, 0.f};

  // bf16 z producer offset (tile pair base): byte 512*T + wby (+2r)
  const int wby = 256 * (q >> 1) + 16 * ln + 8 * (q & 1);
  // swizzle term: function of batch col only
  const int g4  = ((ln >> 2) & 3) << 4;
  // fp8 MX producer offsets (swizzled): tile 2v at o8a, tile 2v+1 at o8a^16
  const int o8a = (512 * v + 32 * ln + 4 * q) ^ g4;
  const int o8b = o8a ^ 16;
  // fp8 MX consumer base (lane's 32B k-row, swizzled): halves rbs, rbs^16
  const int rbs = (512 * q + 32 * ln) ^ g4;

  // ---------------- register-resident A-fragments (weights) ----------------
  bf16x8 wc[5][2];   // W1 (bf16), h1-tiles {2v, 2v+1}
  bf16x8 wl[5];      // Wlin (bf16), lin-tile v
  i32x8  w2x[2][2];  // W2 (fp8 x 2^11), [K-block b][tile i]
  i32x8  w3x[2];     // W3 (fp8 x 2^11), [K-block b], k-tile v
#pragma unroll
  for (int kt = 0; kt < 5; kt++) {
#pragma unroll
    for (int i = 0; i < 2; i++)
      wc[kt][i] = ldw8f(W1 + (size_t)(16 * (2 * v + i) + ln) * NINQ + 32 * kt + 8 * q);
    wl[kt] = ldw8f(Wlin + (size_t)(16 * v + ln) * NINQ + 32 * kt + 8 * q);
  }
#pragma unroll
  for (int b = 0; b < 2; b++) {
#pragma unroll
    for (int i = 0; i < 2; i++)
      w2x[b][i] = ldw32f8(W2 + (size_t)(16 * (2 * v + i) + ln) * NFQ + 128 * b + 32 * q,
                          0x1p11f);
    w3x[b] = ldw32f8(W3 + (size_t)(16 * v + ln) * NFQ + 128 * b + 32 * q, 0x1p11f);
  }

  // ---- biases in registers, pre-scaled for the fp8 pipeline ----
  f32x4 bb1s[2], bb2s[2], bb3;
#pragma unroll
  for (int i = 0; i < 2; i++) {
    f32x4 t1 = *reinterpret_cast<const f32x4*>(b1 + 16 * (2 * v + i) + 4 * q);
    f32x4 t2 = *reinterpret_cast<const f32x4*>(b2 + 16 * (2 * v + i) + 4 * q);
#pragma unroll
    for (int r = 0; r < 4; r++) {
      bb1s[i][r] = t1[r] * 0x1p9f;    // h1' = relu(a*2^9 + b1*2^9)
      bb2s[i][r] = t2[r] * 0x1p16f;   // h2' = relu(d*2^-4 + b2*2^16)
    }
  }
  bb3 = *reinterpret_cast<const f32x4*>(b3 + 16 * v + 4 * q);

  // RK4 state: xs[r] = x[batch ln][xdim 16v+4q+r]
  f32x4 xs, ksum, accl;
  xs = *reinterpret_cast<const f32x4*>(
      x0 + (size_t)(wg * 16 + ln) * NXQ + 16 * v + 4 * q);
  {
    uint2 p;
    p.x = cvtpk(xs[0], xs[1]);
    p.y = cvtpk(xs[2], xs[3]);
    *reinterpret_cast<uint2*>(smem + ZOFF + 512 * v + wby) = p;
  }
  // u B-frag (register-resident): lane holds u[ln][8q+j]
  bf16x8 uf = ldw8f(uin + (size_t)(wg * 16 + ln) * NUQ + 8 * q);
  f32x4 ur0 = zero4, ur1 = zero4;        // raw u[t+1], issued at e==0
  __syncthreads();

#pragma unroll 1
  for (int t = 0; t < TSTEPS; t++) {
#pragma unroll 1
    for (int e = 0; e < 4; e++) {
      // ---- S1 (bf16): h1-tiles {2v,2v+1} = W1 z^T ; lin-tile v in regs ----
      {
        bf16x8 zf[4];
#pragma unroll
        for (int kt = 0; kt < 4; kt++)
          zf[kt] = *reinterpret_cast<const bf16x8*>(smem + ZOFF + 1024 * kt + 16 * lane);
        f32x4 a0 = zero4, a1 = zero4, al = zero4;
#pragma unroll
        for (int kt = 0; kt < 4; kt++) {
          a0 = mfma16(wc[kt][0], zf[kt], a0);
          a1 = mfma16(wc[kt][1], zf[kt], a1);
          al = mfma16(wl[kt], zf[kt], al);
        }
        a0 = mfma16(wc[4][0], uf, a0);
        a1 = mfma16(wc[4][1], uf, a1);
        al = mfma16(wl[4], uf, al);
        accl = al;
#pragma unroll
        for (int i = 0; i < 2; i++) {
          f32x4 d = i ? a1 : a0;
          float e0 = fmaxf(fmaf(d[0], 0x1p9f, bb1s[i][0]), 0.f);
          float e1 = fmaxf(fmaf(d[1], 0x1p9f, bb1s[i][1]), 0.f);
          float e2 = fmaxf(fmaf(d[2], 0x1p9f, bb1s[i][2]), 0.f);
          float e3 = fmaxf(fmaf(d[3], 0x1p9f, bb1s[i][3]), 0.f);
          int wd = 0;
          wd = __builtin_amdgcn_cvt_pk_fp8_f32(e0, e1, wd, false);
          wd = __builtin_amdgcn_cvt_pk_fp8_f32(e2, e3, wd, true);
          *reinterpret_cast<int*>(smem + H1OFF + (i ? o8b : o8a)) = wd;
        }
      }
      bar_lds();
      // ---- S2 (MX fp8 K=128): h2-tiles {2v,2v+1} = W2' h1' ----
      {
        i32x4 l0 = *reinterpret_cast<const i32x4*>(smem + H1OFF + rbs);
        i32x4 l1 = *reinterpret_cast<const i32x4*>(smem + H1OFF + (rbs ^ 16));
        i32x4 l2 = *reinterpret_cast<const i32x4*>(smem + H1OFF + 2048 + rbs);
        i32x4 l3 = *reinterpret_cast<const i32x4*>(smem + H1OFF + 2048 + (rbs ^ 16));
        i32x8 hb0 = {l0[0], l0[1], l0[2], l0[3], l1[0], l1[1], l1[2], l1[3]};
        i32x8 hb1 = {l2[0], l2[1], l2[2], l2[3], l3[0], l3[1], l3[2], l3[3]};
        f32x4 d0 = mfmx(w2x[0][0], hb0, zero4);
        f32x4 d1 = mfmx(w2x[0][1], hb0, zero4);
        d0 = mfmx(w2x[1][0], hb1, d0);
        d1 = mfmx(w2x[1][1], hb1, d1);
#pragma unroll
        for (int i = 0; i < 2; i++) {
          f32x4 d = i ? d1 : d0;
          float e0 = fmaxf(fmaf(d[0], 0x1p-4f, bb2s[i][0]), 0.f);
          float e1 = fmaxf(fmaf(d[1], 0x1p-4f, bb2s[i][1]), 0.f);
          float e2 = fmaxf(fmaf(d[2], 0x1p-4f, bb2s[i][2]), 0.f);
          float e3 = fmaxf(fmaf(d[3], 0x1p-4f, bb2s[i][3]), 0.f);
          int wd = 0;
          wd = __builtin_amdgcn_cvt_pk_fp8_f32(e0, e1, wd, false);
          wd = __builtin_amdgcn_cvt_pk_fp8_f32(e2, e3, wd, true);
          *reinterpret_cast<int*>(smem + H2OFF + (i ? o8b : o8a)) = wd;
        }
      }
      bar_lds();
      // u[t+1]: issue raw loads early (e==0), convert late (e==3)
      if (e == 0 && t + 1 < TSTEPS) {
        const float* up = uin + ((size_t)(t + 1) * BATCH + wg * 16 + ln) * NUQ + 8 * q;
        ur0 = *reinterpret_cast<const f32x4*>(up);
        ur1 = *reinterpret_cast<const f32x4*>(up + 4);
      }
      if (e == 3 && t + 1 < TSTEPS) {
#pragma unroll
        for (int j = 0; j < 4; j++) {
          uf[j]     = (short)f2b(ur0[j]);
          uf[4 + j] = (short)f2b(ur1[j]);
        }
      }
      // ---- S3 (MX fp8 K=128): k-tile v = W3' h2' * 2^-27 + lin + b3 ----
      {
        i32x4 l0 = *reinterpret_cast<const i32x4*>(smem + H2OFF + rbs);
        i32x4 l1 = *reinterpret_cast<const i32x4*>(smem + H2OFF + (rbs ^ 16));
        i32x4 l2 = *reinterpret_cast<const i32x4*>(smem + H2OFF + 2048 + rbs);
        i32x4 l3 = *reinterpret_cast<const i32x4*>(smem + H2OFF + 2048 + (rbs ^ 16));
        i32x8 gb0 = {l0[0], l0[1], l0[2], l0[3], l1[0], l1[1], l1[2], l1[3]};
        i32x8 gb1 = {l2[0], l2[1], l2[2], l2[3], l3[0], l3[1], l3[2], l3[3]};
        f32x4 ka = mfmx(w3x[0], gb0, zero4);
        ka = mfmx(w3x[1], gb1, ka);
        const float wk = (e == 1 || e == 2) ? 2.0f : 1.0f;
        const float cn = (e == 2) ? dt : dth;
        float xe[4];
#pragma unroll
        for (int r = 0; r < 4; r++) {
          float kv = fmaf(ka[r], 0x1p-27f, accl[r] + bb3[r]);
          if (e == 0) ksum[r] = kv; else ksum[r] += wk * kv;
          if (e == 3) { xs[r] += dt6 * ksum[r]; xe[r] = xs[r]; }
          else        { xe[r] = xs[r] + cn * kv; }
        }
        uint2 p;
        p.x = cvtpk(xe[0], xe[1]);
        p.y = cvtpk(xe[2], xe[3]);
        *reinterpret_cast<uint2*>(smem + ZOFF + 512 * v + wby) = p;
        if (e == 3)
          *reinterpret_cast<uint2*>(
              xall + ((size_t)t * BATCH + wg * 16 + ln) * NXQ + 16 * v + 4 * q) = p;
      }
      bar_lds();
    }
  }

  // x_final (f32), vectorized
  *reinterpret_cast<f32x4*>(
      out + NY + (size_t)(wg * 16 + ln) * NXQ + 16 * v + 4 * q) = xs;
}

// ======================= Phase 2: bulk out_net GEMM =========================
// Processes y rows [16*slab .. ) for slabs in [slab0+blk*spw, slab_end).
__global__ __launch_bounds__(512, 2)
void outnet_kernel(const u16* __restrict__ xall,  // [rows][128] bf16
                   const float* __restrict__ Wo1, const float* __restrict__ bo1,
                   const float* __restrict__ Wo2, const float* __restrict__ bo2,
                   const float* __restrict__ Wo3, const float* __restrict__ bo3,
                   float* __restrict__ out,       // y [rows][128] f32
                   int slab0, int slab_end, int spw)
{
  __shared__ u16 h1[2][16][264];
  __shared__ u16 h2[2][16][264];

  const int tid  = threadIdx.x;
  const int lane = tid & 63;
  const int v    = tid >> 6;
  const int ln   = lane & 15;
  const int q    = lane >> 4;
  const int n1   = 16 * v + ln;
  const int n2   = 128 + n1;
  const f32x4 zero4 = {0.f, 0.f, 0.f, 0.f};

  bf16x8 f1[4][2];
#pragma unroll
  for (int kt = 0; kt < 4; kt++) {
    int k = 32 * kt + 8 * q;
    f1[kt][0] = ldw8f(Wo1 + n1 * NXQ + k);
    f1[kt][1] = ldw8f(Wo1 + n2 * NXQ + k);
  }
  bf16x8 f2[8][2];
#pragma unroll
  for (int kt = 0; kt < 8; kt++) {
    int k = 32 * kt + 8 * q;
    f2[kt][0] = ldw8f(Wo2 + n1 * NFQ + k);
    f2[kt][1] = ldw8f(Wo2 + n2 * NFQ + k);
  }
  bf16x8 f3[8];
#pragma unroll
  for (int kt = 0; kt < 8; kt++)
    f3[kt] = ldw8f(Wo3 + n1 * NFQ + 32 * kt + 8 * q);

  const float c1a = bo1[n1], c1b = bo1[n2];
  const float c2a = bo2[n1], c2b = bo2[n2];
  const float c3  = bo3[n1];

  const int s0  = slab0 + (int)blockIdx.x * spw;
  int cnt = slab_end - s0; if (cnt > spw) cnt = spw;
  if (cnt <= 0) return;

  bf16x8 a[4], an[4];
#pragma unroll
  for (int kt = 0; kt < 4; kt++)
    a[kt] = *reinterpret_cast<const bf16x8*>(
        &xall[((size_t)16 * s0 + ln) * NXQ + 32 * kt + 8 * q]);

#pragma unroll 1
  for (int i = 0; i < cnt; i++) {
    const int s = s0 + i, par = i & 1;
    if (i + 1 < cnt) {
#pragma unroll
      for (int kt = 0; kt < 4; kt++)
        an[kt] = *reinterpret_cast<const bf16x8*>(
            &xall[((size_t)16 * (s + 1) + ln) * NXQ + 32 * kt + 8 * q]);
    }
    // o1
    {
      f32x4 d0 = zero4, d1 = zero4;
#pragma unroll
      for (int kt = 0; kt < 4; kt++) {
        d0 = mfma16(a[kt], f1[kt][0], d0);
        d1 = mfma16(a[kt], f1[kt][1], d1);
      }
#pragma unroll
      for (int r = 0; r < 4; r++) {
        h1[par][4 * q + r][n1] = f2b(fmaxf(d0[r] + c1a, 0.f));
        h1[par][4 * q + r][n2] = f2b(fmaxf(d1[r] + c1b, 0.f));
      }
    }
    __syncthreads();
    // o2
    {
      bf16x8 c[8];
#pragma unroll
      for (int kt = 0; kt < 8; kt++)
        c[kt] = *reinterpret_cast<const bf16x8*>(&h1[par][ln][32 * kt + 8 * q]);
      f32x4 e0 = zero4, e1 = zero4;
#pragma unroll
      for (int kt = 0; kt < 8; kt++) {
        e0 = mfma16(c[kt], f2[kt][0], e0);
        e1 = mfma16(c[kt], f2[kt][1], e1);
      }
#pragma unroll
      for (int r = 0; r < 4; r++) {
        h2[par][4 * q + r][n1] = f2b(fmaxf(e0[r] + c2a, 0.f));
        h2[par][4 * q + r][n2] = f2b(fmaxf(e1[r] + c2b, 0.f));
      }
    }
    __syncthreads();
    // o3 -> y (f32); no trailing barrier (ping-pong buffers)
    {
      bf16x8 g[8];
#pragma unroll
      for (int kt = 0; kt < 8; kt++)
        g[kt] = *reinterpret_cast<const bf16x8*>(&h2[par][ln][32 * kt + 8 * q]);
      f32x4 y = zero4;
#pragma unroll
      for (int kt = 0; kt < 8; kt++) y = mfma16(g[kt], f3[kt], y);
#pragma unroll
      for (int r = 0; r < 4; r++)
        out[((size_t)16 * s + 4 * q + r) * NXQ + n1] = y[r] + c3;
    }
#pragma unroll
    for (int kt = 0; kt < 4; kt++) a[kt] = an[kt];
  }
}

extern "C" void kernel_launch(void* const* d_in, const int* in_sizes, int n_in,
                              void* d_out, int out_size, void* d_ws, size_t ws_size,
                              hipStream_t stream) {
  const float* uin  = (const float*)d_in[0];
  const float* x0   = (const float*)d_in[1];
  const float* dtp  = (const float*)d_in[2];
  const float* Wlin = (const float*)d_in[3];
  const float* W1   = (const float*)d_in[4];
  const float* b1   = (const float*)d_in[5];
  const float* W2   = (const float*)d_in[6];
  const float* b2   = (const float*)d_in[7];
  const float* W3   = (const float*)d_in[8];
  const float* b3   = (const float*)d_in[9];
  const float* Wo1  = (const float*)d_in[10];
  const float* bo1  = (const float*)d_in[11];
  const float* Wo2  = (const float*)d_in[12];
  const float* bo2  = (const float*)d_in[13];
  const float* Wo3  = (const float*)d_in[14];
  const float* bo3  = (const float*)d_in[15];
  float* out = (float*)d_out;

  const size_t xall_bytes = NY * sizeof(u16);   // 64 MiB
  const bool ws_ok = (ws_size >= xall_bytes);
  u16* xall = ws_ok ? (u16*)d_ws : (u16*)d_out;  // fallback: front of y region

  scan_kernel<<<dim3(64), dim3(512), 0, stream>>>(
      uin, x0, dtp, Wlin, W1, b1, W2, b2, W3, b3, xall, out);

  const int nslab = TSTEPS * BATCH / 16;        // 16384
  if (ws_ok) {
    const int spw = 32;
    outnet_kernel<<<dim3(nslab / spw), dim3(512), 0, stream>>>(
        xall, Wo1, bo1, Wo2, bo2, Wo3, bo3, out, 0, nslab, spw);
  } else {
    // y[slab s] overwrites x-slabs [2s,2s+2): process [S,2S) in halving
    // passes so clobbered x-slabs are always already consumed.
    for (int S = nslab / 2; S >= 1; S >>= 1) {
      int grid = S < 512 ? S : 512;
      int spw  = (S + grid - 1) / grid;
      outnet_kernel<<<dim3(grid), dim3(512), 0, stream>>>(
          xall, Wo1, bo1, Wo2, bo2, Wo3, bo3, out, S, 2 * S, spw);
    }
    outnet_kernel<<<dim3(1), dim3(512), 0, stream>>>(
        xall, Wo1, bo1, Wo2, bo2, Wo3, bo3, out, 0, 1, 1);
  }
}